// Round 1
// baseline (1332.514 us; speedup 1.0000x reference)
//
#include <hip/hip_runtime.h>
#include <hip/hip_bf16.h>
#include <math.h>

#define N_NODES 50000
#define N_EDGES 800000
#define EP (N_EDGES + N_NODES)   /* 850000 edges incl. self-loops */
#define HID 64
#define HEADS 4
#define F1 (HEADS * HID)         /* 256 */
#define NC 16
#define SLOPE 0.2f

// ---- order-preserving float<->uint key for atomicMax-based segment max ----
__device__ __forceinline__ unsigned fkey(float f) {
    unsigned u = __float_as_uint(f);
    return (u & 0x80000000u) ? ~u : (u | 0x80000000u);
}
__device__ __forceinline__ float funkey(unsigned k) {
    unsigned u = (k & 0x80000000u) ? (k ^ 0x80000000u) : ~k;
    return __uint_as_float(u);
}

__device__ __forceinline__ void edge_sd(int e, const int* __restrict__ ei, int& s, int& d) {
    if (e < N_EDGES) { s = ei[e]; d = ei[N_EDGES + e]; }
    else             { s = e - N_EDGES; d = s; }
}

// ---------------- init ----------------
__global__ void k_zero(float* __restrict__ p, int n) {
    int i = blockIdx.x * blockDim.x + threadIdx.x;
    if (i < n) p[i] = 0.0f;
}

// ---------------- layer 1: xh1 = x @ W1 ; a_src1/a_dst1 dots ----------------
__global__ __launch_bounds__(256) void k_gemm1(
        const float* __restrict__ x, const float* __restrict__ W1,
        const float* __restrict__ att_s, const float* __restrict__ att_d,
        float* __restrict__ xh1, float* __restrict__ a_src, float* __restrict__ a_dst) {
    int r = blockIdx.x;
    int c = threadIdx.x;              // output column 0..255 ; head = c>>6
    __shared__ float xs[HID];
    if (c < HID) xs[c] = x[r * HID + c];
    __syncthreads();
    float acc = 0.0f;
#pragma unroll
    for (int k = 0; k < HID; ++k) acc += xs[k] * W1[k * F1 + c];
    xh1[r * F1 + c] = acc;
    // attention dots: reduce acc*att over the 64 lanes of this wave (one head per wave)
    float ps = acc * att_s[c];        // att_s is [HEADS][HID] = [c]
    float pd = acc * att_d[c];
#pragma unroll
    for (int m = 32; m >= 1; m >>= 1) {
        ps += __shfl_xor(ps, m);
        pd += __shfl_xor(pd, m);
    }
    if ((c & 63) == 0) {
        int h = c >> 6;
        a_src[r * HEADS + h] = ps;
        a_dst[r * HEADS + h] = pd;
    }
}

// ---------------- layer 1 edge passes ----------------
__global__ void k_edge_max1(const int* __restrict__ ei,
                            const float* __restrict__ a_src, const float* __restrict__ a_dst,
                            unsigned* __restrict__ max1) {
    int e = blockIdx.x * blockDim.x + threadIdx.x;
    if (e >= EP) return;
    int s, d; edge_sd(e, ei, s, d);
    const float4 as = *(const float4*)(a_src + s * 4);
    const float4 ad = *(const float4*)(a_dst + d * 4);
    float ev[4] = { as.x + ad.x, as.y + ad.y, as.z + ad.z, as.w + ad.w };
#pragma unroll
    for (int h = 0; h < 4; ++h) {
        float v = ev[h] > 0.0f ? ev[h] : SLOPE * ev[h];
        atomicMax(&max1[d * 4 + h], fkey(v));
    }
}

__global__ void k_edge_sum1(const int* __restrict__ ei,
                            const float* __restrict__ a_src, const float* __restrict__ a_dst,
                            const unsigned* __restrict__ max1, float* __restrict__ denom1) {
    int e = blockIdx.x * blockDim.x + threadIdx.x;
    if (e >= EP) return;
    int s, d; edge_sd(e, ei, s, d);
    const float4 as = *(const float4*)(a_src + s * 4);
    const float4 ad = *(const float4*)(a_dst + d * 4);
    float ev[4] = { as.x + ad.x, as.y + ad.y, as.z + ad.z, as.w + ad.w };
#pragma unroll
    for (int h = 0; h < 4; ++h) {
        float v = ev[h] > 0.0f ? ev[h] : SLOPE * ev[h];
        float ex = expf(v - funkey(max1[d * 4 + h]));
        atomicAdd(&denom1[d * 4 + h], ex);
    }
}

// one block (256 threads) per edge; thread c handles feature c (head = c>>6)
__global__ __launch_bounds__(256) void k_edge_agg1(
        const int* __restrict__ ei,
        const float* __restrict__ a_src, const float* __restrict__ a_dst,
        const unsigned* __restrict__ max1, const float* __restrict__ denom1,
        const float* __restrict__ xh1, float* __restrict__ out1) {
    int e = blockIdx.x;
    int c = threadIdx.x;
    int s, d; edge_sd(e, ei, s, d);
    int h = c >> 6;
    float ev = a_src[s * 4 + h] + a_dst[d * 4 + h];
    ev = ev > 0.0f ? ev : SLOPE * ev;
    float alpha = expf(ev - funkey(max1[d * 4 + h])) / (denom1[d * 4 + h] + 1e-16f);
    atomicAdd(&out1[d * F1 + c], alpha * xh1[s * F1 + c]);
}

// ---------------- ELU + bias ----------------
__global__ void k_elu(const float* __restrict__ out1, const float* __restrict__ b1,
                      float* __restrict__ hbuf, int n) {
    int i = blockIdx.x * blockDim.x + threadIdx.x;
    if (i >= n) return;
    float v = out1[i] + b1[i & (F1 - 1)];
    hbuf[i] = v > 0.0f ? v : (expf(v) - 1.0f);
}

// ---------------- layer 2: xh2 = h @ W2 ; a_src2/a_dst2 ----------------
__global__ __launch_bounds__(64) void k_gemm2(
        const float* __restrict__ hfeat, const float* __restrict__ W2,
        const float* __restrict__ att_s2, const float* __restrict__ att_d2,
        float* __restrict__ xh2, float* __restrict__ a_src2, float* __restrict__ a_dst2) {
    int r = blockIdx.x;
    int t = threadIdx.x;
    int col = t & 15, chunk = t >> 4;    // 4 chunks x 64 k each
    float acc = 0.0f;
#pragma unroll 8
    for (int kk = 0; kk < 64; ++kk) {
        int k = chunk * 64 + kk;
        acc += hfeat[r * F1 + k] * W2[k * NC + col];
    }
    acc += __shfl_down(acc, 32);
    acc += __shfl_down(acc, 16);         // lanes 0..15 now hold full column sums
    float ps = 0.0f, pd = 0.0f;
    if (t < 16) {
        xh2[r * NC + col] = acc;
        ps = acc * att_s2[col];
        pd = acc * att_d2[col];
    }
#pragma unroll
    for (int m = 8; m >= 1; m >>= 1) {
        ps += __shfl_xor(ps, m);
        pd += __shfl_xor(pd, m);
    }
    if (t == 0) { a_src2[r] = ps; a_dst2[r] = pd; }
}

// ---------------- layer 2 edge passes ----------------
__global__ void k_edge_max2(const int* __restrict__ ei,
                            const float* __restrict__ a_src2, const float* __restrict__ a_dst2,
                            unsigned* __restrict__ max2) {
    int e = blockIdx.x * blockDim.x + threadIdx.x;
    if (e >= EP) return;
    int s, d; edge_sd(e, ei, s, d);
    float v = a_src2[s] + a_dst2[d];
    v = v > 0.0f ? v : SLOPE * v;
    atomicMax(&max2[d], fkey(v));
}

__global__ void k_edge_sum2(const int* __restrict__ ei,
                            const float* __restrict__ a_src2, const float* __restrict__ a_dst2,
                            const unsigned* __restrict__ max2, float* __restrict__ denom2) {
    int e = blockIdx.x * blockDim.x + threadIdx.x;
    if (e >= EP) return;
    int s, d; edge_sd(e, ei, s, d);
    float v = a_src2[s] + a_dst2[d];
    v = v > 0.0f ? v : SLOPE * v;
    atomicAdd(&denom2[d], expf(v - funkey(max2[d])));
}

// one thread per (edge, class)
__global__ void k_edge_agg2(const int* __restrict__ ei,
                            const float* __restrict__ a_src2, const float* __restrict__ a_dst2,
                            const unsigned* __restrict__ max2, const float* __restrict__ denom2,
                            const float* __restrict__ xh2, float* __restrict__ out2) {
    int tid = blockIdx.x * blockDim.x + threadIdx.x;
    if (tid >= EP * NC) return;
    int e = tid >> 4, col = tid & 15;
    int s, d; edge_sd(e, ei, s, d);
    float v = a_src2[s] + a_dst2[d];
    v = v > 0.0f ? v : SLOPE * v;
    float alpha = expf(v - funkey(max2[d])) / (denom2[d] + 1e-16f);
    atomicAdd(&out2[d * NC + col], alpha * xh2[s * NC + col]);
}

// ---------------- final log_softmax ----------------
__global__ void k_lsm(const float* __restrict__ out2, const float* __restrict__ b2,
                      float* __restrict__ out) {
    int r = blockIdx.x * blockDim.x + threadIdx.x;
    if (r >= N_NODES) return;
    float v[NC];
    float m = -1e30f;
#pragma unroll
    for (int c = 0; c < NC; ++c) { v[c] = out2[r * NC + c] + b2[c]; m = fmaxf(m, v[c]); }
    float sum = 0.0f;
#pragma unroll
    for (int c = 0; c < NC; ++c) sum += expf(v[c] - m);
    float lse = m + logf(sum);
#pragma unroll
    for (int c = 0; c < NC; ++c) out[r * NC + c] = v[c] - lse;
}

extern "C" void kernel_launch(void* const* d_in, const int* in_sizes, int n_in,
                              void* d_out, int out_size, void* d_ws, size_t ws_size,
                              hipStream_t stream) {
    const float* x        = (const float*)d_in[0];
    const int*   ei       = (const int*)d_in[1];
    const float* W1       = (const float*)d_in[2];
    const float* att_src1 = (const float*)d_in[3];
    const float* att_dst1 = (const float*)d_in[4];
    const float* b1       = (const float*)d_in[5];
    const float* W2       = (const float*)d_in[6];
    const float* att_src2 = (const float*)d_in[7];
    const float* att_dst2 = (const float*)d_in[8];
    const float* b2       = (const float*)d_in[9];
    float* out = (float*)d_out;

    // ---- workspace layout (floats) ----
    float* ws = (float*)d_ws;
    float*    xh1    = ws;                                  // N*256  (reused as h after ELU)
    float*    a_src1 = xh1 + (size_t)N_NODES * F1;          // N*4
    float*    a_dst1 = a_src1 + (size_t)N_NODES * HEADS;    // N*4
    float*    xh2    = a_dst1 + (size_t)N_NODES * HEADS;    // N*16
    float*    a_src2 = xh2 + (size_t)N_NODES * NC;          // N
    float*    a_dst2 = a_src2 + N_NODES;                    // N
    float*    zst    = a_dst2 + N_NODES;                    // zero-init region start:
    float*    out1   = zst;                                 // N*256
    unsigned* max1   = (unsigned*)(out1 + (size_t)N_NODES * F1);  // N*4 (uint keys)
    float*    denom1 = (float*)(max1 + (size_t)N_NODES * HEADS);  // N*4
    unsigned* max2   = (unsigned*)(denom1 + (size_t)N_NODES * HEADS); // N
    float*    denom2 = (float*)(max2 + N_NODES);            // N
    float*    out2   = denom2 + N_NODES;                    // N*16
    size_t zcount = (size_t)((out2 + (size_t)N_NODES * NC) - zst);

    // 1. zero-init the accumulator/max region (max key 0 == below all real keys)
    k_zero<<<(int)((zcount + 255) / 256), 256, 0, stream>>>(zst, (int)zcount);
    // 2. layer-1 GEMM + attention dots
    k_gemm1<<<N_NODES, 256, 0, stream>>>(x, W1, att_src1, att_dst1, xh1, a_src1, a_dst1);
    // 3-5. layer-1 segment softmax + aggregate
    k_edge_max1<<<(EP + 255) / 256, 256, 0, stream>>>(ei, a_src1, a_dst1, max1);
    k_edge_sum1<<<(EP + 255) / 256, 256, 0, stream>>>(ei, a_src1, a_dst1, max1, denom1);
    k_edge_agg1<<<EP, 256, 0, stream>>>(ei, a_src1, a_dst1, max1, denom1, xh1, out1);
    // 6. ELU(out1 + b1) -> h (reuse xh1 buffer)
    k_elu<<<(N_NODES * F1 + 255) / 256, 256, 0, stream>>>(out1, b1, xh1, N_NODES * F1);
    // 7. layer-2 GEMM + attention dots
    k_gemm2<<<N_NODES, 64, 0, stream>>>(xh1, W2, att_src2, att_dst2, xh2, a_src2, a_dst2);
    // 8-10. layer-2 segment softmax + aggregate
    k_edge_max2<<<(EP + 255) / 256, 256, 0, stream>>>(ei, a_src2, a_dst2, max2);
    k_edge_sum2<<<(EP + 255) / 256, 256, 0, stream>>>(ei, a_src2, a_dst2, max2, denom2);
    k_edge_agg2<<<(EP * NC + 255) / 256, 256, 0, stream>>>(ei, a_src2, a_dst2, max2, denom2, xh2, out2);
    // 11. log_softmax -> d_out
    k_lsm<<<(N_NODES + 255) / 256, 256, 0, stream>>>(out2, b2, out);
}

// Round 2
// 479.583 us; speedup vs baseline: 2.7785x; 2.7785x over previous
//
#include <hip/hip_runtime.h>
#include <hip/hip_bf16.h>
#include <math.h>

#define N_NODES 50000
#define N_EDGES 800000
#define EP (N_EDGES + N_NODES)   /* 850000 edges incl. self-loops */
#define HID 64
#define HEADS 4
#define F1 (HEADS * HID)         /* 256 */
#define NC 16
#define SLOPE 0.2f
#define CH 512                   /* edge chunk cached in LDS (layer 1) */
#define CH2 256                  /* edge chunk (layer 2) */

__device__ __forceinline__ void edge_sd(int e, const int* __restrict__ ei, int& s, int& d) {
    if (e < N_EDGES) { s = ei[e]; d = ei[N_EDGES + e]; }
    else             { s = e - N_EDGES; d = s; }
}

// ---------------- init ----------------
__global__ void k_zero_i(int* __restrict__ p, int n) {
    int i = blockIdx.x * blockDim.x + threadIdx.x;
    if (i < n) p[i] = 0;
}

// ---------------- CSR build ----------------
__global__ void k_hist(const int* __restrict__ ei, int* __restrict__ cnt) {
    int e = blockIdx.x * blockDim.x + threadIdx.x;
    if (e >= EP) return;
    int s, d; edge_sd(e, ei, s, d);
    atomicAdd(&cnt[d], 1);
}

// single block, 1024 threads: exclusive scan of cnt -> row_start (+ cursor copy)
__global__ __launch_bounds__(1024) void k_scan(const int* __restrict__ cnt,
        int* __restrict__ row_start, int* __restrict__ cursor) {
    __shared__ int wsum[16];
    __shared__ int s_carry;
    int t = threadIdx.x, lane = t & 63, wid = t >> 6;
    if (t == 0) s_carry = 0;
    __syncthreads();
    for (int b = 0; b < N_NODES; b += 1024) {
        int i = b + t;
        int v = (i < N_NODES) ? cnt[i] : 0;
        int s = v;
#pragma unroll
        for (int off = 1; off < 64; off <<= 1) {
            int x = __shfl_up(s, off);
            if (lane >= off) s += x;
        }
        if (lane == 63) wsum[wid] = s;
        __syncthreads();
        if (t < 16) {
            int w = wsum[t];
#pragma unroll
            for (int off = 1; off < 16; off <<= 1) {
                int x = __shfl_up(w, off);
                if (t >= off) w += x;
            }
            wsum[t] = w;
        }
        __syncthreads();
        int waveoff = (wid == 0) ? 0 : wsum[wid - 1];
        int incl = s + waveoff;
        int excl = incl - v;
        int carry = s_carry;
        if (i < N_NODES) { row_start[i] = carry + excl; cursor[i] = carry + excl; }
        __syncthreads();
        if (t == 1023) s_carry = carry + incl;
        __syncthreads();
    }
    if (threadIdx.x == 0) row_start[N_NODES] = s_carry;
}

// scatter: store SRC node id at the dst-sorted position
__global__ void k_scatter(const int* __restrict__ ei, int* __restrict__ cursor,
                          int* __restrict__ esrc) {
    int e = blockIdx.x * blockDim.x + threadIdx.x;
    if (e >= EP) return;
    int s, d; edge_sd(e, ei, s, d);
    int p = atomicAdd(&cursor[d], 1);
    esrc[p] = s;
}

// ---------------- layer 1: xh1 = x @ W1 ; a_src1/a_dst1 dots ----------------
__global__ __launch_bounds__(256) void k_gemm1(
        const float* __restrict__ x, const float* __restrict__ W1,
        const float* __restrict__ att_s, const float* __restrict__ att_d,
        float* __restrict__ xh1, float* __restrict__ a_src, float* __restrict__ a_dst) {
    int r = blockIdx.x;
    int c = threadIdx.x;              // output column 0..255 ; head = c>>6
    __shared__ float xs[HID];
    if (c < HID) xs[c] = x[r * HID + c];
    __syncthreads();
    float acc = 0.0f;
#pragma unroll
    for (int k = 0; k < HID; ++k) acc += xs[k] * W1[k * F1 + c];
    xh1[(size_t)r * F1 + c] = acc;
    float ps = acc * att_s[c];
    float pd = acc * att_d[c];
#pragma unroll
    for (int m = 32; m >= 1; m >>= 1) {
        ps += __shfl_xor(ps, m);
        pd += __shfl_xor(pd, m);
    }
    if ((c & 63) == 0) {
        int h = c >> 6;
        a_src[r * HEADS + h] = ps;
        a_dst[r * HEADS + h] = pd;
    }
}

// ------- layer 1 fused: segment softmax + aggregate + bias + ELU -------
// one 256-thread block per dst node; wave w == head w; thread t == feature t
__global__ __launch_bounds__(256) void k_csr1(
        const int* __restrict__ row_start, const int* __restrict__ esrc,
        const float* __restrict__ a_src, const float* __restrict__ a_dst,
        const float* __restrict__ xh1, const float* __restrict__ b1,
        float* __restrict__ hbuf) {
    int d = blockIdx.x;
    int t = threadIdx.x, lane = t & 63, h = t >> 6;
    int base = row_start[d], deg = row_start[d + 1] - base;
    __shared__ int   ls[CH];
    __shared__ float lal[HEADS][CH];
    float adh = a_dst[d * HEADS + h];
    // ---- phase 1: online softmax stats (m, den) per head ----
    float m = -1e30f, den = 0.0f;
    for (int c0 = 0; c0 < deg; c0 += CH) {
        int cn = min(CH, deg - c0);
        for (int j = t; j < cn; j += 256) ls[j] = esrc[base + c0 + j];
        __syncthreads();
        float cm = -1e30f;
        for (int j = lane; j < cn; j += 64) {
            float ev = a_src[ls[j] * HEADS + h] + adh;
            ev = ev > 0.0f ? ev : SLOPE * ev;
            lal[h][j] = ev;
            cm = fmaxf(cm, ev);
        }
#pragma unroll
        for (int o = 32; o >= 1; o >>= 1) cm = fmaxf(cm, __shfl_xor(cm, o));
        float cs = 0.0f;
        for (int j = lane; j < cn; j += 64) cs += expf(lal[h][j] - cm);
#pragma unroll
        for (int o = 32; o >= 1; o >>= 1) cs += __shfl_xor(cs, o);
        float mn = fmaxf(m, cm);
        den = den * expf(m - mn) + cs * expf(cm - mn);
        m = mn;
        __syncthreads();
    }
    float inv = 1.0f / (den + 1e-16f);
    // ---- phase 2: aggregate ----
    float acc = 0.0f;
    for (int c0 = 0; c0 < deg; c0 += CH) {
        int cn = min(CH, deg - c0);
        for (int j = t; j < cn; j += 256) ls[j] = esrc[base + c0 + j];
        __syncthreads();
        for (int j = lane; j < cn; j += 64) {
            float ev = a_src[ls[j] * HEADS + h] + adh;
            ev = ev > 0.0f ? ev : SLOPE * ev;
            lal[h][j] = expf(ev - m) * inv;
        }
        __syncthreads();
        for (int j = 0; j < cn; ++j)
            acc += lal[h][j] * xh1[(size_t)ls[j] * F1 + t];
        __syncthreads();
    }
    float v = acc + b1[t];
    hbuf[(size_t)d * F1 + t] = v > 0.0f ? v : (expf(v) - 1.0f);
}

// ---------------- layer 2: xh2 = h @ W2 ; a_src2/a_dst2 ----------------
__global__ __launch_bounds__(64) void k_gemm2(
        const float* __restrict__ hfeat, const float* __restrict__ W2,
        const float* __restrict__ att_s2, const float* __restrict__ att_d2,
        float* __restrict__ xh2, float* __restrict__ a_src2, float* __restrict__ a_dst2) {
    int r = blockIdx.x;
    int t = threadIdx.x;
    int col = t & 15, chunk = t >> 4;    // 4 chunks x 64 k each
    float acc = 0.0f;
#pragma unroll 8
    for (int kk = 0; kk < 64; ++kk) {
        int k = chunk * 64 + kk;
        acc += hfeat[(size_t)r * F1 + k] * W2[k * NC + col];
    }
    acc += __shfl_down(acc, 32);
    acc += __shfl_down(acc, 16);
    float ps = 0.0f, pd = 0.0f;
    if (t < 16) {
        xh2[(size_t)r * NC + col] = acc;
        ps = acc * att_s2[col];
        pd = acc * att_d2[col];
    }
#pragma unroll
    for (int m = 8; m >= 1; m >>= 1) {
        ps += __shfl_xor(ps, m);
        pd += __shfl_xor(pd, m);
    }
    if (t == 0) { a_src2[r] = ps; a_dst2[r] = pd; }
}

// ------- layer 2 fused: segment softmax + aggregate + bias + log_softmax -------
// one wave per dst node; agg maps 64 lanes = 4 edges x 16 classes
__global__ __launch_bounds__(64) void k_csr2(
        const int* __restrict__ row_start, const int* __restrict__ esrc,
        const float* __restrict__ a_src2, const float* __restrict__ a_dst2,
        const float* __restrict__ xh2, const float* __restrict__ b2,
        float* __restrict__ out) {
    int d = blockIdx.x;
    int lane = threadIdx.x;
    int base = row_start[d], deg = row_start[d + 1] - base;
    __shared__ int   ls[CH2];
    __shared__ float lal[CH2];
    float adh = a_dst2[d];
    float m = -1e30f, den = 0.0f;
    for (int c0 = 0; c0 < deg; c0 += CH2) {
        int cn = min(CH2, deg - c0);
        for (int j = lane; j < cn; j += 64) ls[j] = esrc[base + c0 + j];
        __syncthreads();
        float cm = -1e30f;
        for (int j = lane; j < cn; j += 64) {
            float ev = a_src2[ls[j]] + adh;
            ev = ev > 0.0f ? ev : SLOPE * ev;
            lal[j] = ev;
            cm = fmaxf(cm, ev);
        }
#pragma unroll
        for (int o = 32; o >= 1; o >>= 1) cm = fmaxf(cm, __shfl_xor(cm, o));
        float cs = 0.0f;
        for (int j = lane; j < cn; j += 64) cs += expf(lal[j] - cm);
#pragma unroll
        for (int o = 32; o >= 1; o >>= 1) cs += __shfl_xor(cs, o);
        float mn = fmaxf(m, cm);
        den = den * expf(m - mn) + cs * expf(cm - mn);
        m = mn;
        __syncthreads();
    }
    float inv = 1.0f / (den + 1e-16f);
    int c = lane & 15, je = lane >> 4;
    float acc = 0.0f;
    for (int c0 = 0; c0 < deg; c0 += CH2) {
        int cn = min(CH2, deg - c0);
        for (int j = lane; j < cn; j += 64) ls[j] = esrc[base + c0 + j];
        __syncthreads();
        for (int j = lane; j < cn; j += 64) {
            float ev = a_src2[ls[j]] + adh;
            ev = ev > 0.0f ? ev : SLOPE * ev;
            lal[j] = expf(ev - m) * inv;
        }
        __syncthreads();
        for (int j = je; j < cn; j += 4)
            acc += lal[j] * xh2[(size_t)ls[j] * NC + c];
        __syncthreads();
    }
    acc += __shfl_down(acc, 32);
    acc += __shfl_down(acc, 16);       // lanes 0..15: full class sums
    float v = acc + b2[c];
    float mm = v;
#pragma unroll
    for (int o = 8; o >= 1; o >>= 1) mm = fmaxf(mm, __shfl_xor(mm, o));
    float se = expf(v - mm);
#pragma unroll
    for (int o = 8; o >= 1; o >>= 1) se += __shfl_xor(se, o);
    float lse = mm + logf(se);
    if (lane < 16) out[(size_t)d * NC + lane] = v - lse;
}

extern "C" void kernel_launch(void* const* d_in, const int* in_sizes, int n_in,
                              void* d_out, int out_size, void* d_ws, size_t ws_size,
                              hipStream_t stream) {
    const float* x        = (const float*)d_in[0];
    const int*   ei       = (const int*)d_in[1];
    const float* W1       = (const float*)d_in[2];
    const float* att_src1 = (const float*)d_in[3];
    const float* att_dst1 = (const float*)d_in[4];
    const float* b1       = (const float*)d_in[5];
    const float* W2       = (const float*)d_in[6];
    const float* att_src2 = (const float*)d_in[7];
    const float* att_dst2 = (const float*)d_in[8];
    const float* b2       = (const float*)d_in[9];
    float* out = (float*)d_out;

    // ---- workspace layout ----
    float* ws = (float*)d_ws;
    float* xh1    = ws;                                   // N*256
    float* hbuf   = xh1 + (size_t)N_NODES * F1;           // N*256
    float* a_src1 = hbuf + (size_t)N_NODES * F1;          // N*4
    float* a_dst1 = a_src1 + (size_t)N_NODES * HEADS;     // N*4
    float* xh2    = a_dst1 + (size_t)N_NODES * HEADS;     // N*16
    float* a_src2 = xh2 + (size_t)N_NODES * NC;           // N
    float* a_dst2 = a_src2 + N_NODES;                     // N
    int*   cnt       = (int*)(a_dst2 + N_NODES);          // N
    int*   cursor    = cnt + N_NODES;                     // N
    int*   row_start = cursor + N_NODES;                  // N+1
    int*   esrc      = row_start + (N_NODES + 1);         // EP

    // ---- CSR build ----
    k_zero_i<<<(N_NODES + 255) / 256, 256, 0, stream>>>(cnt, N_NODES);
    k_hist<<<(EP + 255) / 256, 256, 0, stream>>>(ei, cnt);
    k_scan<<<1, 1024, 0, stream>>>(cnt, row_start, cursor);
    k_scatter<<<(EP + 255) / 256, 256, 0, stream>>>(ei, cursor, esrc);

    // ---- layer 1 ----
    k_gemm1<<<N_NODES, 256, 0, stream>>>(x, W1, att_src1, att_dst1, xh1, a_src1, a_dst1);
    k_csr1<<<N_NODES, 256, 0, stream>>>(row_start, esrc, a_src1, a_dst1, xh1, b1, hbuf);

    // ---- layer 2 ----
    k_gemm2<<<N_NODES, 64, 0, stream>>>(hbuf, W2, att_src2, att_dst2, xh2, a_src2, a_dst2);
    k_csr2<<<N_NODES, 64, 0, stream>>>(row_start, esrc, a_src2, a_dst2, xh2, b2, out);
}

// Round 3
// 320.526 us; speedup vs baseline: 4.1573x; 1.4962x over previous
//
#include <hip/hip_runtime.h>
#include <hip/hip_bf16.h>
#include <math.h>

#define N_NODES 50000
#define N_EDGES 800000
#define EP (N_EDGES + N_NODES)   /* 850000 edges incl. self-loops */
#define HID 64
#define HEADS 4
#define F1 (HEADS * HID)         /* 256 */
#define NC 16
#define SLOPE 0.2f
#define CH1 256                  /* edge chunk (layer 1) */
#define CH2 256                  /* edge chunk (layer 2) */
#define G1B 1024                 /* gemm grid blocks */

// ---- bf16 helpers (round-to-nearest-even pack, exact unpack) ----
__device__ __forceinline__ unsigned short bf16rn(float f) {
    unsigned u = __float_as_uint(f);
    return (unsigned short)((u + 0x7fffu + ((u >> 16) & 1u)) >> 16);
}
__device__ __forceinline__ float bf_lo(unsigned p) { return __uint_as_float(p << 16); }
__device__ __forceinline__ float bf_hi(unsigned p) { return __uint_as_float(p & 0xffff0000u); }
__device__ __forceinline__ float bf1(unsigned short s) { return __uint_as_float(((unsigned)s) << 16); }

__device__ __forceinline__ void edge_sd(int e, const int* __restrict__ ei, int& s, int& d) {
    if (e < N_EDGES) { s = ei[e]; d = ei[N_EDGES + e]; }
    else             { s = e - N_EDGES; d = s; }
}

// ---------------- init ----------------
__global__ void k_zero_i(int* __restrict__ p, int n) {
    int i = blockIdx.x * blockDim.x + threadIdx.x;
    if (i < n) p[i] = 0;
}

// ---------------- CSR build ----------------
__global__ void k_hist(const int* __restrict__ ei, int* __restrict__ cnt) {
    int e = blockIdx.x * blockDim.x + threadIdx.x;
    if (e >= EP) return;
    int s, d; edge_sd(e, ei, s, d);
    atomicAdd(&cnt[d], 1);
}

// tile-local exclusive scan: 49 blocks x 1024 threads, 1024 elems/block
__global__ __launch_bounds__(1024) void k_scan_local(const int* __restrict__ cnt,
        int* __restrict__ lexcl, int* __restrict__ bsum) {
    __shared__ int wsum[16];
    int t = threadIdx.x, lane = t & 63, wid = t >> 6;
    int i = blockIdx.x * 1024 + t;
    int v = (i < N_NODES) ? cnt[i] : 0;
    int s = v;
#pragma unroll
    for (int off = 1; off < 64; off <<= 1) {
        int x = __shfl_up(s, off);
        if (lane >= off) s += x;
    }
    if (lane == 63) wsum[wid] = s;
    __syncthreads();
    if (t < 16) {
        int w = wsum[t];
#pragma unroll
        for (int off = 1; off < 16; off <<= 1) {
            int x = __shfl_up(w, off);
            if (t >= off) w += x;
        }
        wsum[t] = w;
    }
    __syncthreads();
    int waveoff = (wid == 0) ? 0 : wsum[wid - 1];
    int incl = s + waveoff;
    if (i < N_NODES) lexcl[i] = incl - v;
    if (t == 1023) bsum[blockIdx.x] = incl;
}

// single wave: exclusive scan of the <=64 block sums; write total to row_start[N]
__global__ __launch_bounds__(64) void k_scan_top(int* __restrict__ bsum,
        int* __restrict__ total_slot, int nblk) {
    int t = threadIdx.x;
    int v = (t < nblk) ? bsum[t] : 0;
    int s = v;
#pragma unroll
    for (int off = 1; off < 64; off <<= 1) {
        int x = __shfl_up(s, off);
        if (t >= off) s += x;
    }
    if (t < nblk) bsum[t] = s - v;
    if (t == 63) *total_slot = s;
}

__global__ void k_scan_add(int* __restrict__ row_start, const int* __restrict__ bsum,
                           int* __restrict__ cursor) {
    int i = blockIdx.x * blockDim.x + threadIdx.x;
    if (i >= N_NODES) return;
    int v = row_start[i] + bsum[i >> 10];
    row_start[i] = v;
    cursor[i] = v;
}

__global__ void k_scatter(const int* __restrict__ ei, int* __restrict__ cursor,
                          int* __restrict__ esrc) {
    int e = blockIdx.x * blockDim.x + threadIdx.x;
    if (e >= EP) return;
    int s, d; edge_sd(e, ei, s, d);
    int p = atomicAdd(&cursor[d], 1);
    esrc[p] = s;
}

// ------- layer 1 GEMM: weight-stationary. W1 column in 64 VGPRs/thread -------
// 1024 blocks x 256 threads; block b handles rows b, b+1024, ...
__global__ __launch_bounds__(256) void k_gemm1(
        const float* __restrict__ x, const float* __restrict__ W1,
        const float* __restrict__ att_s, const float* __restrict__ att_d,
        unsigned short* __restrict__ xh1b, float* __restrict__ a_src, float* __restrict__ a_dst) {
    int t = threadIdx.x;                  // output column
    float w[HID];
#pragma unroll
    for (int k = 0; k < HID; ++k) w[k] = W1[k * F1 + t];
    float as_ = att_s[t], ad_ = att_d[t];
    __shared__ float xs[8][HID];
    int b = blockIdx.x;
    for (int i0 = 0; i0 < 49; i0 += 8) {
        __syncthreads();
        // stage up to 8 rows: thread t loads slots (t>>6) and (t>>6)+4, col t&63
        int col = t & 63;
#pragma unroll
        for (int half = 0; half < 2; ++half) {
            int rr = (t >> 6) + half * 4;
            int r = b + (i0 + rr) * G1B;
            if (r < N_NODES) xs[rr][col] = x[(size_t)r * HID + col];
        }
        __syncthreads();
#pragma unroll
        for (int rr = 0; rr < 8; ++rr) {
            int r = b + (i0 + rr) * G1B;
            if (r >= N_NODES) continue;
            const float4* xr = (const float4*)xs[rr];
            float acc = 0.0f;
#pragma unroll
            for (int q = 0; q < 16; ++q) {
                float4 xv = xr[q];
                acc += w[4*q] * xv.x + w[4*q+1] * xv.y + w[4*q+2] * xv.z + w[4*q+3] * xv.w;
            }
            xh1b[(size_t)r * F1 + t] = bf16rn(acc);
            float ps = acc * as_, pd = acc * ad_;
#pragma unroll
            for (int o = 32; o >= 1; o >>= 1) {
                ps += __shfl_xor(ps, o);
                pd += __shfl_xor(pd, o);
            }
            if ((t & 63) == 0) {
                int h = t >> 6;
                a_src[r * HEADS + h] = ps;
                a_dst[r * HEADS + h] = pd;
            }
        }
    }
}

// ------- layer 1 fused: single-pass online softmax + aggregate + bias + ELU -------
// 128 threads/block; group g = t>>5 (32 lanes) == head g.
// softmax: group lanes loop edges. aggregate: thread t owns features 2t,2t+1 (head g).
__global__ __launch_bounds__(128) void k_csr1(
        const int* __restrict__ row_start, const int* __restrict__ esrc,
        const float* __restrict__ a_src, const float* __restrict__ a_dst,
        const unsigned short* __restrict__ xh1b, const float* __restrict__ b1,
        unsigned* __restrict__ hbufb) {
    int d = blockIdx.x;
    int t = threadIdx.x, l = t & 31, g = t >> 5;
    int base = row_start[d], deg = row_start[d + 1] - base;
    __shared__ int   ls[CH1];
    __shared__ float lal[HEADS][CH1];
    float adh = a_dst[d * HEADS + g];
    float m = -1e30f, den = 0.0f, acc0 = 0.0f, acc1 = 0.0f;
    for (int c0 = 0; c0 < deg; c0 += CH1) {
        int cn = min(CH1, deg - c0);
        for (int j = t; j < cn; j += 128) ls[j] = esrc[base + c0 + j];
        __syncthreads();
        float cm = -1e30f;
        for (int j = l; j < cn; j += 32) {
            float ev = a_src[ls[j] * HEADS + g] + adh;
            ev = ev > 0.0f ? ev : SLOPE * ev;
            lal[g][j] = ev;
            cm = fmaxf(cm, ev);
        }
#pragma unroll
        for (int o = 16; o >= 1; o >>= 1) cm = fmaxf(cm, __shfl_xor(cm, o));
        float mn = fmaxf(m, cm);
        float sc = expf(m - mn);
        acc0 *= sc; acc1 *= sc; den *= sc; m = mn;
        float cs = 0.0f;
        for (int j = l; j < cn; j += 32) {
            float wj = expf(lal[g][j] - m);
            lal[g][j] = wj;
            cs += wj;
        }
#pragma unroll
        for (int o = 16; o >= 1; o >>= 1) cs += __shfl_xor(cs, o);
        den += cs;
        // aggregate this chunk: bf16 row gather, 2 features per thread
        for (int j = 0; j < cn; ++j) {
            float wj = lal[g][j];
            unsigned pv = *(const unsigned*)(xh1b + (size_t)ls[j] * F1 + 2 * t);
            acc0 += wj * bf_lo(pv);
            acc1 += wj * bf_hi(pv);
        }
        __syncthreads();
    }
    float inv = 1.0f / (den + 1e-16f);
    float2 bb = *(const float2*)(b1 + 2 * t);
    float v0 = acc0 * inv + bb.x;
    float v1 = acc1 * inv + bb.y;
    v0 = v0 > 0.0f ? v0 : (expf(v0) - 1.0f);
    v1 = v1 > 0.0f ? v1 : (expf(v1) - 1.0f);
    hbufb[(size_t)d * (F1 / 2) + t] = (unsigned)bf16rn(v0) | ((unsigned)bf16rn(v1) << 16);
}

// ------- layer 2 GEMM: W2 in 64 VGPRs/thread, one wave/block -------
__global__ __launch_bounds__(64) void k_gemm2(
        const unsigned* __restrict__ hbufb, const float* __restrict__ W2,
        const float* __restrict__ att_s2, const float* __restrict__ att_d2,
        unsigned short* __restrict__ xh2b, float* __restrict__ a_src2, float* __restrict__ a_dst2) {
    int t = threadIdx.x, col = t & 15, ch = t >> 4;
    float w2[64];
#pragma unroll
    for (int kk = 0; kk < 64; ++kk) w2[kk] = W2[(ch * 64 + kk) * NC + col];
    float as_ = att_s2[col], ad_ = att_d2[col];
    __shared__ float xs[4 * 68];          // padded: chunk base = ch*68 (bank-spread)
    for (int i = 0; i < 49; ++i) {
        int r = blockIdx.x + i * G1B;
        if (r >= N_NODES) break;
        // load h row (256 bf16 = 128 uints): 2 uints per thread -> 4 floats to LDS
        uint2 pp = *(const uint2*)(hbufb + (size_t)r * (F1 / 2) + 2 * t);
        int kbase = 4 * t;                // k index of first element
        int dst = (kbase >> 6) * 68 + (kbase & 63);
        float4 xv4 = make_float4(bf_lo(pp.x), bf_hi(pp.x), bf_lo(pp.y), bf_hi(pp.y));
        *(float4*)(xs + dst) = xv4;
        float acc = 0.0f;
        const float4* x4 = (const float4*)(xs + ch * 68);
#pragma unroll
        for (int q = 0; q < 16; ++q) {
            float4 xv = x4[q];
            acc += w2[4*q] * xv.x + w2[4*q+1] * xv.y + w2[4*q+2] * xv.z + w2[4*q+3] * xv.w;
        }
        acc += __shfl_down(acc, 32);
        acc += __shfl_down(acc, 16);      // lanes 0..15: full sums
        float ps = 0.0f, pd = 0.0f;
        if (t < 16) {
            xh2b[(size_t)r * NC + col] = bf16rn(acc);
            ps = acc * as_;
            pd = acc * ad_;
        }
#pragma unroll
        for (int o = 8; o >= 1; o >>= 1) {
            ps += __shfl_xor(ps, o);
            pd += __shfl_xor(pd, o);
        }
        if (t == 0) { a_src2[r] = ps; a_dst2[r] = pd; }
    }
}

// ------- layer 2 fused: single-pass softmax + aggregate + bias + log_softmax -------
// one wave per dst; aggregate maps 64 lanes = 4 edges x 16 classes
__global__ __launch_bounds__(64) void k_csr2(
        const int* __restrict__ row_start, const int* __restrict__ esrc,
        const float* __restrict__ a_src2, const float* __restrict__ a_dst2,
        const unsigned short* __restrict__ xh2b, const float* __restrict__ b2,
        float* __restrict__ out) {
    int d = blockIdx.x;
    int l = threadIdx.x;
    int base = row_start[d], deg = row_start[d + 1] - base;
    __shared__ int   ls[CH2];
    __shared__ float lal[CH2];
    float adh = a_dst2[d];
    int c = l & 15, je = l >> 4;
    float m = -1e30f, den = 0.0f, acc = 0.0f;
    for (int c0 = 0; c0 < deg; c0 += CH2) {
        int cn = min(CH2, deg - c0);
        for (int j = l; j < cn; j += 64) ls[j] = esrc[base + c0 + j];
        float cm = -1e30f;
        for (int j = l; j < cn; j += 64) {
            float ev = a_src2[ls[j]] + adh;
            ev = ev > 0.0f ? ev : SLOPE * ev;
            lal[j] = ev;
            cm = fmaxf(cm, ev);
        }
#pragma unroll
        for (int o = 32; o >= 1; o >>= 1) cm = fmaxf(cm, __shfl_xor(cm, o));
        float mn = fmaxf(m, cm);
        float sc = expf(m - mn);
        acc *= sc; den *= sc; m = mn;
        float cs = 0.0f;
        for (int j = l; j < cn; j += 64) {
            float wj = expf(lal[j] - m);
            lal[j] = wj;
            cs += wj;
        }
#pragma unroll
        for (int o = 32; o >= 1; o >>= 1) cs += __shfl_xor(cs, o);
        den += cs;
        for (int j = je; j < cn; j += 4)
            acc += lal[j] * bf1(xh2b[(size_t)ls[j] * NC + c]);
    }
    acc += __shfl_down(acc, 32);
    acc += __shfl_down(acc, 16);          // lanes 0..15: class sums
    float v = acc / (den + 1e-16f) + b2[c];
    float mm = v;
#pragma unroll
    for (int o = 8; o >= 1; o >>= 1) mm = fmaxf(mm, __shfl_xor(mm, o));
    float se = expf(v - mm);
#pragma unroll
    for (int o = 8; o >= 1; o >>= 1) se += __shfl_xor(se, o);
    float lse = mm + logf(se);
    if (l < 16) out[(size_t)d * NC + l] = v - lse;
}

extern "C" void kernel_launch(void* const* d_in, const int* in_sizes, int n_in,
                              void* d_out, int out_size, void* d_ws, size_t ws_size,
                              hipStream_t stream) {
    const float* x        = (const float*)d_in[0];
    const int*   ei       = (const int*)d_in[1];
    const float* W1       = (const float*)d_in[2];
    const float* att_src1 = (const float*)d_in[3];
    const float* att_dst1 = (const float*)d_in[4];
    const float* b1       = (const float*)d_in[5];
    const float* W2       = (const float*)d_in[6];
    const float* att_src2 = (const float*)d_in[7];
    const float* att_dst2 = (const float*)d_in[8];
    const float* b2       = (const float*)d_in[9];
    float* out = (float*)d_out;

    // ---- workspace layout ----
    char* p = (char*)d_ws;
    unsigned short* xh1b  = (unsigned short*)p; p += (size_t)N_NODES * F1 * 2;     // 25.6MB
    unsigned*       hbufb = (unsigned*)p;       p += (size_t)N_NODES * (F1/2) * 4; // 25.6MB
    unsigned short* xh2b  = (unsigned short*)p; p += (size_t)N_NODES * NC * 2;     // 1.6MB
    float* a_src1 = (float*)p; p += (size_t)N_NODES * HEADS * 4;
    float* a_dst1 = (float*)p; p += (size_t)N_NODES * HEADS * 4;
    float* a_src2 = (float*)p; p += (size_t)N_NODES * 4;
    float* a_dst2 = (float*)p; p += (size_t)N_NODES * 4;
    int* cnt       = (int*)p;  p += (size_t)N_NODES * 4;
    int* cursor    = (int*)p;  p += (size_t)N_NODES * 4;
    int* row_start = (int*)p;  p += (size_t)(N_NODES + 1) * 4;
    int* bsum      = (int*)p;  p += 64 * 4;
    int* esrc      = (int*)p;  p += (size_t)EP * 4;

    const int NT = (N_NODES + 1023) / 1024;   // 49 scan tiles

    // ---- CSR build ----
    k_zero_i<<<(N_NODES + 255) / 256, 256, 0, stream>>>(cnt, N_NODES);
    k_hist<<<(EP + 255) / 256, 256, 0, stream>>>(ei, cnt);
    k_scan_local<<<NT, 1024, 0, stream>>>(cnt, row_start, bsum);
    k_scan_top<<<1, 64, 0, stream>>>(bsum, row_start + N_NODES, NT);
    k_scan_add<<<(N_NODES + 255) / 256, 256, 0, stream>>>(row_start, bsum, cursor);
    k_scatter<<<(EP + 255) / 256, 256, 0, stream>>>(ei, cursor, esrc);

    // ---- layer 1 ----
    k_gemm1<<<G1B, 256, 0, stream>>>(x, W1, att_src1, att_dst1, xh1b, a_src1, a_dst1);
    k_csr1<<<N_NODES, 128, 0, stream>>>(row_start, esrc, a_src1, a_dst1, xh1b, b1, hbufb);

    // ---- layer 2 ----
    k_gemm2<<<G1B, 64, 0, stream>>>(hbufb, W2, att_src2, att_dst2, xh2b, a_src2, a_dst2);
    k_csr2<<<N_NODES, 64, 0, stream>>>(row_start, esrc, a_src2, a_dst2, xh2b, b2, out);
}